// Round 5
// baseline (212.968 us; speedup 1.0000x reference)
//
#include <hip/hip_runtime.h>

// SelfAttention (B=4, C=256, H=W=64): fused projections + split-K flash attention.
// Round 8: r7 (95us) was NEUTRAL vs r6 despite halving LDS traffic and VALU ->
// falsifies "aggregate work" as the limiter. Counters: issue occupancy ~49%,
// conflicts ~3% of budget, OccupancyPercent 27% (grid 512 = 2 blocks/CU).
// Per-tile wall time 7.1K cycles vs ~1K identifiable critical path = exposed
// latency in the per-tile barrier convoy with nothing else resident to fill it.
// Fix (single variable): split-K x4 -> 1024 blocks (4/CU, 24 waves = 75%
// occupancy ceiling), 16 tiles/block; combine merges 4 partials. Falls back to
// split-K x2 if ws_size is too small. Wave structure/numerics unchanged.

#define B_ 4
#define C_ 256
#define N_ 4096
#define CQK 32
#define LOG2E 1.44269504088896340736f

typedef __attribute__((ext_vector_type(8))) short short8;
typedef __attribute__((ext_vector_type(4))) short short4v;
typedef __attribute__((ext_vector_type(2))) unsigned int uint2v;
typedef __attribute__((ext_vector_type(16))) float f32x16;
typedef __attribute__((ext_vector_type(4))) float f32x4;

__device__ __forceinline__ unsigned short f2bf(float f) {
  unsigned int u = __builtin_bit_cast(unsigned int, f);
  u = (u + 0x7fffu + ((u >> 16) & 1u)) >> 16;  // RNE
  return (unsigned short)u;
}
__device__ __forceinline__ float bf2f(unsigned short s) {
  unsigned int u = ((unsigned int)s) << 16;
  return __builtin_bit_cast(float, u);
}
__device__ __forceinline__ short f32tof16(float f) {
  const _Float16 hf = (_Float16)f;
  return __builtin_bit_cast(short, hf);
}
// pack two f32 -> two bf16 (RNE), one instruction
__device__ __forceinline__ unsigned int cvtpk(float lo, float hi) {
  unsigned int r;
  asm("v_cvt_pk_bf16_f32 %0, %1, %2" : "=v"(r) : "v"(lo), "v"(hi));
  return r;
}
__device__ __forceinline__ f32x16 mfma16(short8 a, short8 b, f32x16 c) {
  return __builtin_amdgcn_mfma_f32_32x32x16_bf16(a, b, c, 0, 0, 0);
}
// swizzled element index into bf16 LDS tiles (16B granules XORed by row)
__device__ __forceinline__ int swz64(int row, int col) {  // rows of 64 bf16
  return row * 64 + ((((col >> 3) ^ row) & 7) << 3) + (col & 7);
}

#define WAITCNT(s) asm volatile("s_waitcnt " s ::: "memory")
#define BARRIER()                         \
  do {                                    \
    __builtin_amdgcn_s_barrier();         \
    asm volatile("" ::: "memory");        \
  } while (0)

// ---------------- kernel 1: prep (x transpose+split, weight splits) ----------
__global__ __launch_bounds__(256) void k_prep(
    const float* __restrict__ x, unsigned short* __restrict__ xthi,
    unsigned short* __restrict__ xtlo,
    const float* __restrict__ Wq, const float* __restrict__ Wk,
    const float* __restrict__ Wv,
    unsigned short* __restrict__ wqh, unsigned short* __restrict__ wql,
    unsigned short* __restrict__ wkh, unsigned short* __restrict__ wkl,
    unsigned short* __restrict__ wvh, unsigned short* __restrict__ wvl) {
  __shared__ __align__(16) float tile[64 * 65];
  const int bi = blockIdx.x;
  const int t = threadIdx.x;
  if (bi < 1024) {
    const int it = bi & 63, ct = (bi >> 6) & 3, b = bi >> 8;
    const int i0 = it * 64, c0 = ct * 64;
    {
      const int i = t & 63, cb = t >> 6;
#pragma unroll
      for (int z = 0; z < 16; ++z) {
        const int c = z * 4 + cb;
        tile[i * 65 + c] = x[(b * C_ + c0 + c) * N_ + i0 + i];
      }
    }
    __syncthreads();
    {
      const int ii = t >> 2, p = t & 3;
      short8 h0, h1, l0, l1;
#pragma unroll
      for (int e = 0; e < 16; ++e) {
        const float f = tile[ii * 65 + p * 16 + e];
        const unsigned short hb = f2bf(f);
        const unsigned short lb = f2bf(f - bf2f(hb));
        if (e < 8) { h0[e] = (short)hb; l0[e] = (short)lb; }
        else       { h1[e - 8] = (short)hb; l1[e - 8] = (short)lb; }
      }
      const int base = (b * N_ + i0 + ii) * C_ + c0 + p * 16;
      *(short8*)(xthi + base) = h0;
      *(short8*)(xthi + base + 8) = h1;
      *(short8*)(xtlo + base) = l0;
      *(short8*)(xtlo + base + 8) = l1;
    }
  } else {
    const int e = (bi - 1024) * 256 + t;  // < 81920
    const float* src; unsigned short *hi, *lo; int idx;
    if (e < 8192)        { src = Wq; hi = wqh; lo = wql; idx = e; }
    else if (e < 16384)  { src = Wk; hi = wkh; lo = wkl; idx = e - 8192; }
    else                 { src = Wv; hi = wvh; lo = wvl; idx = e - 16384; }
    float f = src[idx];
    if (e < 8192) f *= LOG2E;  // log2-domain scores: fold log2(e) into Wq
    const unsigned short h = f2bf(f);
    hi[idx] = h;
    lo[idx] = f2bf(f - bf2f(h));
  }
}

// ---------------- kernel 2: fused q/k/v projection GEMM ----------------
__global__ __launch_bounds__(256) void k_proj(
    const unsigned short* __restrict__ wqh, const unsigned short* __restrict__ wql,
    const unsigned short* __restrict__ wkh, const unsigned short* __restrict__ wkl,
    const unsigned short* __restrict__ wvh, const unsigned short* __restrict__ wvl,
    const unsigned short* __restrict__ xthi, const unsigned short* __restrict__ xtlo,
    const float* __restrict__ bq, const float* __restrict__ bk,
    const float* __restrict__ bv,
    unsigned short* __restrict__ qhg, unsigned short* __restrict__ qlg,
    unsigned short* __restrict__ khg, unsigned short* __restrict__ klg,
    unsigned short* __restrict__ vg) {
  __shared__ __align__(16) char sm[33792];
  unsigned short* awh = (unsigned short*)sm;       // [64][64] W hi (swizzled)
  unsigned short* awl = awh + 4096;
  unsigned short* bxh = awl + 4096;                // [64][64] x^T hi
  unsigned short* bxl = bxh + 4096;
  float* qt = (float*)sm;                          // epilogue reuse: [64][65] f32

  const int it = blockIdx.x, ot = blockIdx.y, b = blockIdx.z;
  const int i0 = it * 64, o0 = ot * 64;
  const int t = threadIdx.x, lane = t & 63, w = t >> 6, h = lane >> 5;
  const int mb = w >> 1, nb = w & 1;
  const int srow = t >> 2, sp = t & 3;

  const int og = o0 + srow;
  const unsigned short *wh, *wl;
  if (og < 32)      { wh = wqh + og * C_;        wl = wql + og * C_; }
  else if (og < 64) { wh = wkh + (og - 32) * C_; wl = wkl + (og - 32) * C_; }
  else              { wh = wvh + (og - 64) * C_; wl = wvl + (og - 64) * C_; }
  const unsigned short* xh = xthi + (b * N_ + i0 + srow) * C_;
  const unsigned short* xl = xtlo + (b * N_ + i0 + srow) * C_;

  f32x16 acc;
#pragma unroll
  for (int e = 0; e < 16; ++e) acc[e] = 0.f;
  const int m = 32 * mb + (lane & 31);
  const int n = 32 * nb + (lane & 31);

  for (int kt = 0; kt < 4; ++kt) {
    const int cb = kt * 64 + sp * 16;
    *(short8*)&awh[swz64(srow, sp * 16)]     = *(const short8*)(wh + cb);
    *(short8*)&awh[swz64(srow, sp * 16 + 8)] = *(const short8*)(wh + cb + 8);
    *(short8*)&awl[swz64(srow, sp * 16)]     = *(const short8*)(wl + cb);
    *(short8*)&awl[swz64(srow, sp * 16 + 8)] = *(const short8*)(wl + cb + 8);
    *(short8*)&bxh[swz64(srow, sp * 16)]     = *(const short8*)(xh + cb);
    *(short8*)&bxh[swz64(srow, sp * 16 + 8)] = *(const short8*)(xh + cb + 8);
    *(short8*)&bxl[swz64(srow, sp * 16)]     = *(const short8*)(xl + cb);
    *(short8*)&bxl[swz64(srow, sp * 16 + 8)] = *(const short8*)(xl + cb + 8);
    __syncthreads();
#pragma unroll
    for (int kk = 0; kk < 4; ++kk) {
      const int kb = kk * 16 + h * 8;
      const short8 ah  = *(const short8*)&awh[swz64(m, kb)];
      const short8 al2 = *(const short8*)&awl[swz64(m, kb)];
      const short8 bh  = *(const short8*)&bxh[swz64(n, kb)];
      const short8 bl2 = *(const short8*)&bxl[swz64(n, kb)];
      acc = mfma16(ah, bh, acc);   // hi*hi
      acc = mfma16(ah, bl2, acc);  // hi*lo
      acc = mfma16(al2, bh, acc);  // lo*hi
    }
    __syncthreads();
  }

  if (ot > 0) {  // v epilogue: direct [B][C][N] bf16 store
#pragma unroll
    for (int e = 0; e < 16; ++e) {
      const int r = 32 * mb + (e & 3) + 8 * (e >> 2) + 4 * h;
      const int oc = o0 - 64 + r;
      vg[(b * C_ + oc) * N_ + i0 + n] = f2bf(acc[e] + bv[oc]);
    }
  } else {  // q/k epilogue: LDS transpose -> [B][N][32] hi/lo
#pragma unroll
    for (int e = 0; e < 16; ++e) {
      const int r = 32 * mb + (e & 3) + 8 * (e >> 2) + 4 * h;
      const float bias = (r < 32) ? bq[r] * LOG2E : bk[r - 32];
      qt[r * 65 + n] = acc[e] + bias;
    }
    __syncthreads();
    const int ii = t >> 2;
    short8 hv0, hv1, lv0, lv1;
#pragma unroll
    for (int e = 0; e < 16; ++e) {
      const float f = qt[(sp * 16 + e) * 65 + ii];
      const unsigned short hb = f2bf(f);
      const unsigned short lb = f2bf(f - bf2f(hb));
      if (e < 8) { hv0[e] = (short)hb; lv0[e] = (short)lb; }
      else       { hv1[e - 8] = (short)hb; lv1[e - 8] = (short)lb; }
    }
    if (sp < 2) {
      const int base = (b * N_ + i0 + ii) * CQK + sp * 16;
      *(short8*)(qhg + base) = hv0; *(short8*)(qhg + base + 8) = hv1;
      *(short8*)(qlg + base) = lv0; *(short8*)(qlg + base + 8) = lv1;
    } else {
      const int base = (b * N_ + i0 + ii) * CQK + sp * 16 - 32;
      *(short8*)(khg + base) = hv0; *(short8*)(khg + base + 8) = hv1;
      *(short8*)(klg + base) = lv0; *(short8*)(klg + base + 8) = lv1;
    }
  }
}

// ---------------- kernel 3: producer/consumer flash attention ----------------
// Grid = 256<<LOGS blocks x 384 threads (6 waves). NSPLIT = 1<<LOGS key-splits.
// blk = qt*(4*NSPLIT) + b*NSPLIT + part; blk&7 -> XCD gets fixed part (+b
// parity) so per-XCD K/V stays L2-resident.
// Waves 0-3: fat PV consumers (64 channels). Waves 4,5: S producers (rows
// 0-31 / 32-63), every tile, register (m,l). P double-buffered; 1 barrier/tile.
// Scores log2-domain; Opart: [blk][wave 4][lane 64][64 f16].
template <int LOGS>
__global__ __launch_bounds__(384, 3) void k_flash(
    const unsigned short* __restrict__ qhg, const unsigned short* __restrict__ qlg,
    const unsigned short* __restrict__ khg, const unsigned short* __restrict__ klg,
    const unsigned short* __restrict__ vg,
    unsigned short* __restrict__ Opart, float* __restrict__ mlpart) {
  constexpr int NSPLIT = 1 << LOGS;
  constexpr int NTILES = 64 >> LOGS;   // 64-key tiles per block
  __shared__ __align__(16) char sm[16928];
  char* Pb0 = sm;                          // [64][128B] bf16 P, swizzled
  char* Pb1 = sm + 8192;
  float* alphaA = (float*)(sm + 16384);    // [2][64]
  float* chgF = (float*)(sm + 16896);      // [2][2] per-half "max changed"

  const int blk = blockIdx.x;
  const int part = blk & (NSPLIT - 1);
  const int b = (blk >> LOGS) & 3;
  const int qt_ = blk >> (LOGS + 2);
  const int q0 = qt_ * 64;
  const int jbase = part * (4096 >> LOGS);
  const int t = threadIdx.x, lane = t & 63, w = t >> 6, h = lane >> 5;
  const int l31 = lane & 31;

  if (w < 4) {
    // ================= fat PV consumer =================
    const int c0 = 64 * w + l31;
    const unsigned short* vsrc0 = vg + (size_t)(b * C_ + c0) * N_ + jbase + h * 8;
    const unsigned short* vsrc1 = vsrc0 + (size_t)32 * N_;
    f32x16 acc0, acc1, acc2, acc3;
#pragma unroll
    for (int e = 0; e < 16; ++e) {
      acc0[e] = 0.f; acc1[e] = 0.f; acc2[e] = 0.f; acc3[e] = 0.f;
    }
    short8 vf0[4], vf1[4];
#pragma unroll
    for (int kk = 0; kk < 4; ++kk) {
      vf0[kk] = *(const short8*)(vsrc0 + kk * 16);
      vf1[kk] = *(const short8*)(vsrc1 + kk * 16);
    }
    WAITCNT("lgkmcnt(0)");
    BARRIER();  // prologue: P(0)/alpha(0)/flags(0) ready

#pragma unroll 2
    for (int kt = 0; kt < NTILES; ++kt) {
      const char* pb = (kt & 1) ? Pb1 : Pb0;
      const float* alp = alphaA + (kt & 1) * 64;
      const float cA = chgF[(kt & 1) * 2];
      const float cB = chgF[(kt & 1) * 2 + 1];
      if (cA != 0.f) {  // rescale q-rows 0..31 (acc0, acc2)
#pragma unroll
        for (int eq = 0; eq < 4; ++eq) {
          const f32x4 av = *(const f32x4*)(alp + 8 * eq + 4 * h);
#pragma unroll
          for (int q = 0; q < 4; ++q) {
            acc0[4 * eq + q] *= av[q];
            acc2[4 * eq + q] *= av[q];
          }
        }
      }
      if (cB != 0.f) {  // rescale q-rows 32..63 (acc1, acc3)
#pragma unroll
        for (int eq = 0; eq < 4; ++eq) {
          const f32x4 av = *(const f32x4*)(alp + 32 + 8 * eq + 4 * h);
#pragma unroll
          for (int q = 0; q < 4; ++q) {
            acc1[4 * eq + q] *= av[q];
            acc3[4 * eq + q] *= av[q];
          }
        }
      }
      __builtin_amdgcn_s_setprio(1);
#pragma unroll
      for (int kk = 0; kk < 4; ++kk) {
        const int phys = (2 * kk + h) ^ (l31 & 7);
        const short8 pa0 = *(const short8*)(pb + l31 * 128 + phys * 16);
        const short8 pa1 = *(const short8*)(pb + (32 + l31) * 128 + phys * 16);
        acc0 = mfma16(pa0, vf0[kk], acc0);
        acc1 = mfma16(pa1, vf0[kk], acc1);
        acc2 = mfma16(pa0, vf1[kk], acc2);
        acc3 = mfma16(pa1, vf1[kk], acc3);
      }
      __builtin_amdgcn_s_setprio(0);
      if (kt + 1 < NTILES) {  // prefetch V(kt+1) to regs (L2-resident)
#pragma unroll
        for (int kk = 0; kk < 4; ++kk) {
          vf0[kk] = *(const short8*)(vsrc0 + (kt + 1) * 64 + kk * 16);
          vf1[kk] = *(const short8*)(vsrc1 + (kt + 1) * 64 + kk * 16);
        }
      }
      WAITCNT("lgkmcnt(0)");
      BARRIER();
    }
    // epilogue: lane-major coalesced store (64 f16 per lane, contiguous)
    {
      unsigned short* dst = Opart + (size_t)blk * 16384 + (w * 64 + lane) * 64;
      short8 o[8];
#pragma unroll
      for (int e = 0; e < 8; ++e) {
        o[0][e] = f32tof16(acc0[e]);      o[1][e] = f32tof16(acc0[8 + e]);
        o[2][e] = f32tof16(acc1[e]);      o[3][e] = f32tof16(acc1[8 + e]);
        o[4][e] = f32tof16(acc2[e]);      o[5][e] = f32tof16(acc2[8 + e]);
        o[6][e] = f32tof16(acc3[e]);      o[7][e] = f32tof16(acc3[8 + e]);
      }
#pragma unroll
      for (int q = 0; q < 8; ++q) *(short8*)(dst + 8 * q) = o[q];
    }
  } else {
    // ================= S producer (rows sw*32..sw*32+31) =================
    const int sw = w - 4;
    const int srow = sw * 32 + l31;
    short8 qfh[2], qfl[2];
    {
      const unsigned short* qph = qhg + (size_t)(b * N_ + q0 + srow) * CQK + h * 8;
      const unsigned short* qpl = qlg + (size_t)(b * N_ + q0 + srow) * CQK + h * 8;
#pragma unroll
      for (int kk = 0; kk < 2; ++kk) {
        qfh[kk] = *(const short8*)(qph + kk * 16);
        qfl[kk] = *(const short8*)(qpl + kk * 16);
      }
    }
    const unsigned short* kph = khg + (size_t)(b * N_ + jbase + l31) * CQK + h * 8;
    const unsigned short* kpl = klg + (size_t)(b * N_ + jbase + l31) * CQK + h * 8;
    short8 kfh[2][2], kfl[2][2];  // [jt][kk], single buffer (issue-after-use)
    float m_run = -1e30f, l_run = 0.f;

    auto loadK = [&](int tau) {
#pragma unroll
      for (int jt = 0; jt < 2; ++jt)
#pragma unroll
        for (int kk = 0; kk < 2; ++kk) {
          kfh[jt][kk] = *(const short8*)(kph + tau * 2048 + jt * 1024 + kk * 16);
          kfl[jt][kk] = *(const short8*)(kpl + tau * 2048 + jt * 1024 + kk * 16);
        }
    };
    auto s_step = [&](int tau) {
      f32x16 s0, s1;  // S^T: s0 = j 0..31, s1 = j 32..63 (cols = q = l31)
#pragma unroll
      for (int e = 0; e < 16; ++e) { s0[e] = 0.f; s1[e] = 0.f; }
      __builtin_amdgcn_s_setprio(1);
#pragma unroll
      for (int kk = 0; kk < 2; ++kk) {
        s0 = mfma16(kfh[0][kk], qfh[kk], s0);
        s0 = mfma16(kfh[0][kk], qfl[kk], s0);
        s0 = mfma16(kfl[0][kk], qfh[kk], s0);
        s1 = mfma16(kfh[1][kk], qfh[kk], s1);
        s1 = mfma16(kfh[1][kk], qfl[kk], s1);
        s1 = mfma16(kfl[1][kk], qfh[kk], s1);
      }
      __builtin_amdgcn_s_setprio(0);
      if (tau + 1 < NTILES) loadK(tau + 1);  // K(tau) consumed; window = softmax
      // tree max over 32 regs, then partner merge (lane^32 holds other j-half)
      float mx8[8];
#pragma unroll
      for (int i2 = 0; i2 < 4; ++i2) {
        mx8[i2] = fmaxf(fmaxf(s0[4 * i2], s0[4 * i2 + 1]),
                        fmaxf(s0[4 * i2 + 2], s0[4 * i2 + 3]));
        mx8[4 + i2] = fmaxf(fmaxf(s1[4 * i2], s1[4 * i2 + 1]),
                            fmaxf(s1[4 * i2 + 2], s1[4 * i2 + 3]));
      }
      float mx = fmaxf(fmaxf(fmaxf(mx8[0], mx8[1]), fmaxf(mx8[2], mx8[3])),
                       fmaxf(fmaxf(mx8[4], mx8[5]), fmaxf(mx8[6], mx8[7])));
      mx = fmaxf(mx, __shfl_xor(mx, 32));
      const float mnew = fmaxf(m_run, mx);
      const bool up = mnew > m_run;
      const float al = __builtin_exp2f(m_run - mnew);
#pragma unroll
      for (int e = 0; e < 16; ++e) s0[e] = __builtin_exp2f(s0[e] - mnew);
#pragma unroll
      for (int e = 0; e < 16; ++e) s1[e] = __builtin_exp2f(s1[e] - mnew);
      float t8[8];
#pragma unroll
      for (int i2 = 0; i2 < 4; ++i2) {
        t8[i2] = (s0[4 * i2] + s0[4 * i2 + 1]) + (s0[4 * i2 + 2] + s0[4 * i2 + 3]);
        t8[4 + i2] = (s1[4 * i2] + s1[4 * i2 + 1]) + (s1[4 * i2 + 2] + s1[4 * i2 + 3]);
      }
      float ts = ((t8[0] + t8[1]) + (t8[2] + t8[3])) +
                 ((t8[4] + t8[5]) + (t8[6] + t8[7]));
      ts += __shfl_xor(ts, 32);
      l_run = l_run * al + ts;
      // pack bf16 (cvt_pk) + write P[tau&1]
      char* Pw = (tau & 1) ? Pb1 : Pb0;
#pragma unroll
      for (int q = 0; q < 4; ++q) {
        uint2v u0, u1;
        u0[0] = cvtpk(s0[4 * q], s0[4 * q + 1]);
        u0[1] = cvtpk(s0[4 * q + 2], s0[4 * q + 3]);
        u1[0] = cvtpk(s1[4 * q], s1[4 * q + 1]);
        u1[1] = cvtpk(s1[4 * q + 2], s1[4 * q + 3]);
        const int ph0 = q ^ (srow & 7);
        const int ph1 = (4 + q) ^ (srow & 7);
        *(uint2v*)(Pw + srow * 128 + ph0 * 16 + 8 * h) = u0;
        *(uint2v*)(Pw + srow * 128 + ph1 * 16 + 8 * h) = u1;
      }
      const unsigned long long ba = __ballot(up);
      if (h == 0) alphaA[(tau & 1) * 64 + srow] = al;
      if (lane == 0) chgF[(tau & 1) * 2 + sw] = ba ? 1.f : 0.f;
      m_run = mnew;
    };

    loadK(0);
    s_step(0);
    WAITCNT("lgkmcnt(0)");
    BARRIER();
#pragma unroll 2
    for (int kt = 0; kt < NTILES; ++kt) {
      if (kt + 1 < NTILES) s_step(kt + 1);
      WAITCNT("lgkmcnt(0)");
      BARRIER();
    }
    if (h == 0) {  // m is log2-domain; combine uses exp2
      mlpart[blk * 128 + srow] = m_run;
      mlpart[blk * 128 + 64 + srow] = l_run;
    }
  }
}

// ---------------- kernel 4: combine partials + residual ----------------
// Opart: [blk][w 4][lane 64][64 f16]; for (c,i): wave = c>>6,
// lane = (c&31) + 32*((i>>2)&1), slot = ((i>>5) + 2*((c>>5)&1))*16 + e,
// e = (i&3) + 4*((i>>3)&3). m's are log2-domain -> exp2.
template <int LOGS>
__global__ __launch_bounds__(256) void k_combine(
    const unsigned short* __restrict__ Opart, const float* __restrict__ mlpart,
    const float* __restrict__ x, const float* __restrict__ gamma,
    float* __restrict__ out) {
  constexpr int NS = 1 << LOGS;
  const int cb = blockIdx.x;
  const int b = cb & 3, qt_ = cb >> 2;
  const int q0 = qt_ * 64;
  const int base = (qt_ << (LOGS + 2)) | (b << LOGS);
  const int t = threadIdx.x;
  const int i = t & 63, cg = t >> 6;

  float mv[NS], lv[NS];
#pragma unroll
  for (int s = 0; s < NS; ++s) {
    mv[s] = mlpart[(base + s) * 128 + i];
    lv[s] = mlpart[(base + s) * 128 + 64 + i];
  }
  float M = mv[0];
#pragma unroll
  for (int s = 1; s < NS; ++s) M = fmaxf(M, mv[s]);
  float wv[NS];
  float denom = 0.f;
#pragma unroll
  for (int s = 0; s < NS; ++s) {
    wv[s] = __builtin_exp2f(mv[s] - M);
    denom += wv[s] * lv[s];
  }
  const float gm = gamma[0];
  const float inv = gm / denom;
  float sc[NS];
#pragma unroll
  for (int s = 0; s < NS; ++s) sc[s] = wv[s] * inv;

  const int hh = (i >> 2) & 1;
  const int e = (i & 3) + 4 * ((i >> 3) & 3);
  const int rs = i >> 5;
#pragma unroll 4
  for (int c = cg; c < C_; c += 4) {
    const int off = (c >> 6) * 4096 + ((c & 31) + 32 * hh) * 64 +
                    (rs + 2 * ((c >> 5) & 1)) * 16 + e;
    float acc = 0.f;
#pragma unroll
    for (int s = 0; s < NS; ++s) {
      const unsigned short* p =
          Opart + (size_t)(base + s) * 16384 + off;
      acc += sc[s] * (float)__builtin_bit_cast(_Float16, *p);
    }
    const int g = (b * C_ + c) * N_ + q0 + i;
    out[g] = acc + x[g];
  }
}

// ---------------- launch ----------------
extern "C" void kernel_launch(void* const* d_in, const int* in_sizes, int n_in,
                              void* d_out, int out_size, void* d_ws, size_t ws_size,
                              hipStream_t stream) {
  const float* x     = (const float*)d_in[0];
  const float* Wq    = (const float*)d_in[1];
  const float* bq    = (const float*)d_in[2];
  const float* Wk    = (const float*)d_in[3];
  const float* bk    = (const float*)d_in[4];
  const float* Wv    = (const float*)d_in[5];
  const float* bv    = (const float*)d_in[6];
  const float* gamma = (const float*)d_in[7];
  float* out = (float*)d_out;
  (void)in_sizes; (void)n_in; (void)out_size;

  char* ws = (char*)d_ws;
  size_t off = 0;
  auto carve = [&](size_t bytes) -> char* {
    char* p = ws + off;
    off += (bytes + 255) & ~(size_t)255;
    return p;
  };
  unsigned short* xthi = (unsigned short*)carve((size_t)B_ * N_ * C_ * 2);
  unsigned short* xtlo = (unsigned short*)carve((size_t)B_ * N_ * C_ * 2);
  unsigned short* wqh  = (unsigned short*)carve(32 * 256 * 2);
  unsigned short* wql  = (unsigned short*)carve(32 * 256 * 2);
  unsigned short* wkh  = (unsigned short*)carve(32 * 256 * 2);
  unsigned short* wkl  = (unsigned short*)carve(32 * 256 * 2);
  unsigned short* wvh  = (unsigned short*)carve(256 * 256 * 2);
  unsigned short* wvl  = (unsigned short*)carve(256 * 256 * 2);
  unsigned short* qhg  = (unsigned short*)carve((size_t)B_ * N_ * CQK * 2);
  unsigned short* qlg  = (unsigned short*)carve((size_t)B_ * N_ * CQK * 2);
  unsigned short* khg  = (unsigned short*)carve((size_t)B_ * N_ * CQK * 2);
  unsigned short* klg  = (unsigned short*)carve((size_t)B_ * N_ * CQK * 2);
  unsigned short* vg   = (unsigned short*)carve((size_t)B_ * C_ * N_ * 2);

  // choose split-K factor by available workspace: x4 needs 1024 partials
  const size_t opart4 = (size_t)1024 * 16384 * 2 + (size_t)1024 * 128 * 4 + 4096;
  const bool big = ws_size > off + opart4;
  const int nblk = big ? 1024 : 512;
  unsigned short* Opart = (unsigned short*)carve((size_t)nblk * 16384 * 2);
  float* mlpart = (float*)carve((size_t)nblk * 128 * 4);

  k_prep<<<1344, 256, 0, stream>>>(x, xthi, xtlo, Wq, Wk, Wv,
                                   wqh, wql, wkh, wkl, wvh, wvl);
  k_proj<<<dim3(64, 5, B_), 256, 0, stream>>>(wqh, wql, wkh, wkl, wvh, wvl,
                                              xthi, xtlo, bq, bk, bv,
                                              qhg, qlg, khg, klg, vg);
  if (big) {
    k_flash<2><<<1024, 384, 0, stream>>>(qhg, qlg, khg, klg, vg, Opart, mlpart);
    k_combine<2><<<256, 256, 0, stream>>>(Opart, mlpart, x, gamma, out);
  } else {
    k_flash<1><<<512, 384, 0, stream>>>(qhg, qlg, khg, klg, vg, Opart, mlpart);
    k_combine<1><<<256, 256, 0, stream>>>(Opart, mlpart, x, gamma, out);
  }
}